// Round 2
// baseline (805.034 us; speedup 1.0000x reference)
//
#include <hip/hip_runtime.h>
#include <math.h>

#define N_NODES 1024
#define BATCH   64
#define F_IN    128     // D_IN + UNITS
#define UNITS   64
#define NUM_M   5
#define CAP     192     // ELL row capacity (mean nnz ~31, max ~55 for this seed)
#define FT      8       // spmm f-tile (8 floats) -> 48 KB LDS, under 64 KB default cap
#define LDSROW  12      // padded LDS row stride (floats); 12 mod 32 spreads banks

// ---------------- ELL build: compact dense L rows, deterministic n-order ----
__global__ void ell_build(const float* __restrict__ L, int* __restrict__ cnt,
                          int* __restrict__ cols, float* __restrict__ vals) {
    int row  = blockIdx.x * (blockDim.x >> 6) + (threadIdx.x >> 6);
    int lane = threadIdx.x & 63;
    if (row >= N_NODES) return;
    const float* Lr = L + (size_t)row * N_NODES;
    int base = 0;
    for (int seg = 0; seg < N_NODES; seg += 64) {
        float v = Lr[seg + lane];
        bool nz = (v != 0.0f);
        unsigned long long bal = __ballot(nz);
        int off = __popcll(bal & ((1ull << lane) - 1ull));
        if (nz) {
            int idx = base + off;
            if (idx < CAP) { cols[row * CAP + idx] = seg + lane; vals[row * CAP + idx] = v; }
        }
        base += __popcll(bal);
    }
    if (base > CAP) base = CAP;
    int padded = (base + 7) & ~7;
    if (padded > CAP) padded = CAP;
    for (int idx = base + lane; idx < padded; idx += 64) {
        cols[row * CAP + idx] = 0; vals[row * CAP + idx] = 0.0f;
    }
    if (lane == 0) cnt[row] = padded;
}

// ---------------- W' prep: fold Chebyshev recurrence into weights -----------
// W layout: [fan_in=640][nout], fan_in index = k*5 + m.
// W'[m][k][j]: m0 = W0-W3-W4, m1 = W1, m2 = W2, m3 = 2*W3, m4 = 2*W4
__global__ void wprep(const float* __restrict__ W, float* __restrict__ Wp, int nout) {
    int idx = blockIdx.x * blockDim.x + threadIdx.x;
    int total = NUM_M * F_IN * nout;
    if (idx >= total) return;
    int j = idx % nout;
    int k = (idx / nout) % F_IN;
    int m = idx / (nout * F_IN);
    const float* Wk = W + (size_t)(k * NUM_M) * nout;
    float v;
    if (m == 0)      v = Wk[0 * nout + j] - Wk[3 * nout + j] - Wk[4 * nout + j];
    else if (m == 3) v = 2.0f * Wk[3 * nout + j];
    else if (m == 4) v = 2.0f * Wk[4 * nout + j];
    else             v = Wk[(size_t)m * nout + j];
    Wp[idx] = v;
}

// ---------------- xin builders ---------------------------------------------
__global__ void build_xin1(const float* __restrict__ inp, const float* __restrict__ hx,
                           float* __restrict__ X, int row0, int nrows) {
    int t = blockIdx.x * blockDim.x + threadIdx.x;
    int total = nrows * 32;              // 32 float4 per row
    if (t >= total) return;
    int i = t >> 5, q = t & 31;
    size_t g = (size_t)(row0 + i);
    float4 v;
    if (q < 16) v = ((const float4*)(inp + g * 64))[q];
    else        v = ((const float4*)(hx  + g * 64))[q - 16];
    ((float4*)(X + (size_t)i * F_IN))[q] = v;
}

__global__ void build_xin2(const float* __restrict__ inp, const float* __restrict__ hx,
                           const float* __restrict__ OUT1, float* __restrict__ X,
                           int row0, int nrows) {
    int t = blockIdx.x * blockDim.x + threadIdx.x;
    int total = nrows * 32;
    if (t >= total) return;
    int i = t >> 5, q = t & 31;
    size_t g = (size_t)(row0 + i);
    float4 v;
    if (q < 16) v = ((const float4*)(inp + g * 64))[q];
    else {
        float4 h = ((const float4*)(hx + g * 64))[q - 16];
        float4 r = ((const float4*)(OUT1 + (size_t)i * F_IN))[q - 16]; // r = cols 0..63
        v = make_float4(h.x * r.x, h.y * r.y, h.z * r.z, h.w * r.w);
    }
    ((float4*)(X + (size_t)i * F_IN))[q] = v;
}

// ---------------- SpMM: Y[b,m,f] = sum_n L[m,n] * X[b,n,f] -----------------
// grid = (F_IN/FT, bc); block = 256; static LDS = 1024*LDSROW*4 = 48 KB
__global__ __launch_bounds__(256) void spmm(
        const int* __restrict__ cnt, const int* __restrict__ cols,
        const float* __restrict__ vals, const float* __restrict__ X,
        float* __restrict__ Y) {
    __shared__ float lds[N_NODES * LDSROW];  // [1024][12]
    int b  = blockIdx.y;
    int f0 = blockIdx.x * FT;
    const float* Xb = X + (size_t)b * N_NODES * F_IN;
    for (int v = threadIdx.x; v < N_NODES * (FT / 4); v += 256) {
        int n = v >> 1, q = v & 1;
        float4 d = *(const float4*)(Xb + (size_t)n * F_IN + f0 + q * 4);
        *(float4*)(lds + n * LDSROW + q * 4) = d;
    }
    __syncthreads();
    int fg = threadIdx.x & 1;                 // 2 f-subgroups of 4
    int mg = threadIdx.x >> 1;                // 128 m-groups
    float* Yb = Y + (size_t)b * N_NODES * F_IN + f0 + fg * 4;
    for (int m = mg; m < N_NODES; m += 128) {
        int nn = cnt[m];
        const int*   cm = cols + m * CAP;
        const float* vm = vals + m * CAP;
        float4 acc = make_float4(0.f, 0.f, 0.f, 0.f);
        for (int j = 0; j < nn; j += 8) {     // nn is a multiple of 8
            int4   c0 = *(const int4*)(cm + j);
            int4   c1 = *(const int4*)(cm + j + 4);
            float4 w0 = *(const float4*)(vm + j);
        float4 w1 = *(const float4*)(vm + j + 4);
            int cc[8] = {c0.x, c0.y, c0.z, c0.w, c1.x, c1.y, c1.z, c1.w};
            float ww[8] = {w0.x, w0.y, w0.z, w0.w, w1.x, w1.y, w1.z, w1.w};
            #pragma unroll
            for (int u = 0; u < 8; ++u) {
                float4 x = *(const float4*)(lds + cc[u] * LDSROW + fg * 4);
                acc.x += ww[u] * x.x; acc.y += ww[u] * x.y;
                acc.z += ww[u] * x.z; acc.w += ww[u] * x.w;
            }
        }
        *(float4*)(Yb + (size_t)m * F_IN) = acc;
    }
}

// ---------------- Projection: out = act(bias + sum_m Xm @ W'[m]) -----------
// 128-row x NOUT tile per block, 256 threads, 8x(NOUT/16) regs per thread
template <int NOUT, int ACT>
__global__ __launch_bounds__(256, 2) void proj(
        const float* __restrict__ X0, const float* __restrict__ X1,
        const float* __restrict__ X2, const float* __restrict__ X3,
        const float* __restrict__ X4,
        const float* __restrict__ Wp, const float* __restrict__ bias,
        float* __restrict__ out) {
    __shared__ float xt[32][132];            // [k][i] transposed, padded
    __shared__ float wt[32][NOUT + 4];       // [k][j], padded
    constexpr int JT = NOUT / 16;
    int i0 = blockIdx.x * 128;
    int tx = threadIdx.x & 15;               // j-group
    int ty = threadIdx.x >> 4;               // i-group (8 consecutive rows)
    float acc[8][JT];
    #pragma unroll
    for (int r = 0; r < 8; ++r)
        #pragma unroll
        for (int c = 0; c < JT; ++c) acc[r][c] = 0.f;

    const float* Xs[NUM_M] = {X0, X1, X2, X3, X4};
    #pragma unroll
    for (int m = 0; m < NUM_M; ++m) {
        const float* Xm = Xs[m];
        const float* Wm = Wp + (size_t)m * F_IN * NOUT;
        for (int k0 = 0; k0 < F_IN; k0 += 32) {
            __syncthreads();
            for (int v = threadIdx.x; v < 128 * 8; v += 256) {   // stage X tile (transposed)
                int i = v >> 3, q = v & 7;
                float4 d = *(const float4*)(Xm + (size_t)(i0 + i) * F_IN + k0 + q * 4);
                xt[q * 4 + 0][i] = d.x; xt[q * 4 + 1][i] = d.y;
                xt[q * 4 + 2][i] = d.z; xt[q * 4 + 3][i] = d.w;
            }
            for (int v = threadIdx.x; v < 32 * (NOUT / 4); v += 256) {  // stage W tile
                int kk = v / (NOUT / 4), q = v % (NOUT / 4);
                float4 d = *(const float4*)(Wm + (size_t)(k0 + kk) * NOUT + q * 4);
                *(float4*)(&wt[kk][q * 4]) = d;
            }
            __syncthreads();
            for (int kk = 0; kk < 32; ++kk) {
                float xv[8], wv[JT];
                *(float4*)&xv[0] = *(const float4*)&xt[kk][ty * 8];
                *(float4*)&xv[4] = *(const float4*)&xt[kk][ty * 8 + 4];
                #pragma unroll
                for (int c = 0; c < JT; c += 4)
                    *(float4*)&wv[c] = *(const float4*)&wt[kk][tx * JT + c];
                #pragma unroll
                for (int r = 0; r < 8; ++r)
                    #pragma unroll
                    for (int c = 0; c < JT; ++c)
                        acc[r][c] += xv[r] * wv[c];
            }
        }
    }
    float bv[JT];
    #pragma unroll
    for (int c = 0; c < JT; ++c) bv[c] = bias[tx * JT + c];
    #pragma unroll
    for (int r = 0; r < 8; ++r) {
        int row = i0 + ty * 8 + r;
        float* orow = out + (size_t)row * NOUT + tx * JT;
        #pragma unroll
        for (int c = 0; c < JT; c += 4) {
            float4 v;
            float a0 = acc[r][c + 0] + bv[c + 0];
            float a1 = acc[r][c + 1] + bv[c + 1];
            float a2 = acc[r][c + 2] + bv[c + 2];
            float a3 = acc[r][c + 3] + bv[c + 3];
            if (ACT) { v.x = tanhf(a0); v.y = tanhf(a1); v.z = tanhf(a2); v.w = tanhf(a3); }
            else {
                v.x = 1.f / (1.f + expf(-a0)); v.y = 1.f / (1.f + expf(-a1));
                v.z = 1.f / (1.f + expf(-a2)); v.w = 1.f / (1.f + expf(-a3));
            }
            *(float4*)(orow + c) = v;
        }
    }
}

// ---------------- Final gating: out = u*hx + (1-u)*c -----------------------
__global__ void finalize(const float* __restrict__ OUT1, const float* __restrict__ OUT2,
                         const float* __restrict__ hx, float* __restrict__ out,
                         int row0, int nrows) {
    int t = blockIdx.x * blockDim.x + threadIdx.x;
    int total = nrows * 16;                  // 16 float4 per row of 64
    if (t >= total) return;
    int i = t >> 4, q = t & 15;
    size_t g = (size_t)(row0 + i);
    float4 u = *(const float4*)(OUT1 + (size_t)i * F_IN + 64 + q * 4);
    float4 c = *(const float4*)(OUT2 + (size_t)i * UNITS + q * 4);
    float4 h = *(const float4*)(hx + g * 64 + q * 4);
    float4 o;
    o.x = u.x * h.x + (1.f - u.x) * c.x;
    o.y = u.y * h.y + (1.f - u.y) * c.y;
    o.z = u.z * h.z + (1.f - u.z) * c.z;
    o.w = u.w * h.w + (1.f - u.w) * c.w;
    *(float4*)(out + g * 64 + q * 4) = o;
}

// ---------------------------------------------------------------------------
extern "C" void kernel_launch(void* const* d_in, const int* in_sizes, int n_in,
                              void* d_out, int out_size, void* d_ws, size_t ws_size,
                              hipStream_t stream) {
    const float* inp = (const float*)d_in[0];
    const float* hx  = (const float*)d_in[1];
    const float* L0  = (const float*)d_in[2];
    const float* L1  = (const float*)d_in[3];
    const float* W1  = (const float*)d_in[4];
    const float* b1  = (const float*)d_in[5];
    const float* W2  = (const float*)d_in[6];
    const float* b2  = (const float*)d_in[7];
    float* out = (float*)d_out;

    char* ws = (char*)d_ws;
    size_t off = 0;
    auto carve = [&](size_t bytes) -> char* {
        off = (off + 255) & ~(size_t)255;
        char* p = ws + off;
        off += bytes;
        return p;
    };
    // fixed region
    int*   cnt0  = (int*)  carve(N_NODES * sizeof(int));
    int*   cols0 = (int*)  carve((size_t)N_NODES * CAP * sizeof(int));
    float* vals0 = (float*)carve((size_t)N_NODES * CAP * sizeof(float));
    int*   cnt1  = (int*)  carve(N_NODES * sizeof(int));
    int*   cols1 = (int*)  carve((size_t)N_NODES * CAP * sizeof(int));
    float* vals1 = (float*)carve((size_t)N_NODES * CAP * sizeof(float));
    float* Wp1   = (float*)carve((size_t)NUM_M * F_IN * 128 * sizeof(float));
    float* Wp2   = (float*)carve((size_t)NUM_M * F_IN * 64 * sizeof(float));

    // dynamic chunking over batch
    size_t per_batch = (size_t)N_NODES * F_IN * 4 * 6      // X0,A,B,C,D,OUT1
                     + (size_t)N_NODES * UNITS * 4;        // OUT2
    size_t fixed_end = (off + 255) & ~(size_t)255;
    size_t avail = (ws_size > fixed_end + 4096) ? (ws_size - fixed_end - 4096) : per_batch;
    int Bc = (int)(avail / per_batch);
    if (Bc < 1) Bc = 1;
    if (Bc > BATCH) Bc = BATCH;

    size_t xb = (size_t)N_NODES * F_IN * sizeof(float);    // per-batch X-buffer bytes
    float* X0   = (float*)carve((size_t)Bc * xb);
    float* A    = (float*)carve((size_t)Bc * xb);
    float* Bm   = (float*)carve((size_t)Bc * xb);
    float* C    = (float*)carve((size_t)Bc * xb);
    float* D    = (float*)carve((size_t)Bc * xb);
    float* OUT1 = (float*)carve((size_t)Bc * xb);                          // [bc*1024][128]
    float* OUT2 = (float*)carve((size_t)Bc * N_NODES * UNITS * sizeof(float)); // [bc*1024][64]

    ell_build<<<N_NODES / 4, 256, 0, stream>>>(L0, cnt0, cols0, vals0);
    ell_build<<<N_NODES / 4, 256, 0, stream>>>(L1, cnt1, cols1, vals1);
    wprep<<<(NUM_M * F_IN * 128 + 255) / 256, 256, 0, stream>>>(W1, Wp1, 128);
    wprep<<<(NUM_M * F_IN * 64 + 255) / 256, 256, 0, stream>>>(W2, Wp2, 64);

    for (int b0 = 0; b0 < BATCH; b0 += Bc) {
        int bc = (BATCH - b0 < Bc) ? (BATCH - b0) : Bc;
        int nrows = bc * N_NODES;
        int row0 = b0 * N_NODES;
        dim3 sg(F_IN / FT, bc);

        build_xin1<<<(nrows * 32 + 255) / 256, 256, 0, stream>>>(inp, hx, X0, row0, nrows);
        spmm<<<sg, 256, 0, stream>>>(cnt0, cols0, vals0, X0, A);
        spmm<<<sg, 256, 0, stream>>>(cnt1, cols1, vals1, X0, Bm);
        spmm<<<sg, 256, 0, stream>>>(cnt0, cols0, vals0, A, C);
        spmm<<<sg, 256, 0, stream>>>(cnt1, cols1, vals1, Bm, D);
        proj<128, 0><<<nrows / 128, 256, 0, stream>>>(X0, A, Bm, C, D, Wp1, b1, OUT1);

        build_xin2<<<(nrows * 32 + 255) / 256, 256, 0, stream>>>(inp, hx, OUT1, X0, row0, nrows);
        spmm<<<sg, 256, 0, stream>>>(cnt0, cols0, vals0, X0, A);
        spmm<<<sg, 256, 0, stream>>>(cnt1, cols1, vals1, X0, Bm);
        spmm<<<sg, 256, 0, stream>>>(cnt0, cols0, vals0, A, C);
        spmm<<<sg, 256, 0, stream>>>(cnt1, cols1, vals1, Bm, D);
        proj<64, 1><<<nrows / 128, 256, 0, stream>>>(X0, A, Bm, C, D, Wp2, b2, OUT2);

        finalize<<<(nrows * 16 + 255) / 256, 256, 0, stream>>>(OUT1, OUT2, hx, out, row0, nrows);
    }
}

// Round 3
// 619.803 us; speedup vs baseline: 1.2989x; 1.2989x over previous
//
#include <hip/hip_runtime.h>
#include <math.h>

#define N_NODES 1024
#define BATCH   64
#define F_IN    128     // D_IN + UNITS
#define UNITS   64
#define NUM_M   5
#define CAP     192     // ELL row capacity (mean nnz ~31, max ~55 for this seed)
#define FT      8       // diffusion f-tile
#define NFT     16      // F_IN / FT

// ---------------- ELL build: compact dense L rows, deterministic n-order ----
__global__ void ell_build(const float* __restrict__ L, int* __restrict__ cnt,
                          int* __restrict__ cols, float* __restrict__ vals) {
    int row  = blockIdx.x * (blockDim.x >> 6) + (threadIdx.x >> 6);
    int lane = threadIdx.x & 63;
    if (row >= N_NODES) return;
    const float* Lr = L + (size_t)row * N_NODES;
    int base = 0;
    for (int seg = 0; seg < N_NODES; seg += 64) {
        float v = Lr[seg + lane];
        bool nz = (v != 0.0f);
        unsigned long long bal = __ballot(nz);
        int off = __popcll(bal & ((1ull << lane) - 1ull));
        if (nz) {
            int idx = base + off;
            if (idx < CAP) { cols[row * CAP + idx] = seg + lane; vals[row * CAP + idx] = v; }
        }
        base += __popcll(bal);
    }
    if (base > CAP) base = CAP;
    int padded = (base + 7) & ~7;
    if (padded > CAP) padded = CAP;
    for (int idx = base + lane; idx < padded; idx += 64) {
        cols[row * CAP + idx] = 0; vals[row * CAP + idx] = 0.0f;
    }
    if (lane == 0) cnt[row] = padded;
}

// ---------------- W' prep: fold Chebyshev recurrence into weights -----------
// W layout: [fan_in=640][nout], fan_in index = k*5 + m.
// W'[m][k][j]: m0 = W0-W3-W4, m1 = W1, m2 = W2, m3 = 2*W3, m4 = 2*W4
__global__ void wprep(const float* __restrict__ W, float* __restrict__ Wp, int nout) {
    int idx = blockIdx.x * blockDim.x + threadIdx.x;
    int total = NUM_M * F_IN * nout;
    if (idx >= total) return;
    int j = idx % nout;
    int k = (idx / nout) % F_IN;
    int m = idx / (nout * F_IN);
    const float* Wk = W + (size_t)(k * NUM_M) * nout;
    float v;
    if (m == 0)      v = Wk[0 * nout + j] - Wk[3 * nout + j] - Wk[4 * nout + j];
    else if (m == 3) v = 2.0f * Wk[3 * nout + j];
    else if (m == 4) v = 2.0f * Wk[4 * nout + j];
    else             v = Wk[(size_t)m * nout + j];
    Wp[idx] = v;
}

// ---------------- diffuse4: A,B,C,D f-tiles from one staged xin tile --------
// grid = (NFT, bc), block = 256, LDS = 64 KB (X-tile + temp-tile)
// xin read on the fly: cols<64 from inp, cols>=64 from hx (* r for RMUL).
// Outputs written in tiled layout: buf[((b*NFT + ft)*1024 + m)*8 + f]
template <int RMUL>
__global__ __launch_bounds__(256) void diffuse4(
        const int* __restrict__ cnt0, const int* __restrict__ cols0, const float* __restrict__ vals0,
        const int* __restrict__ cnt1, const int* __restrict__ cols1, const float* __restrict__ vals1,
        const float* __restrict__ inp, const float* __restrict__ hx, const float* __restrict__ r1,
        float* __restrict__ A, float* __restrict__ Bm,
        float* __restrict__ C, float* __restrict__ D, int row0) {
    __shared__ float ldsX[N_NODES * FT];
    __shared__ float ldsT[N_NODES * FT];
    const int b = blockIdx.y, f0 = blockIdx.x * FT;
    const int tid = threadIdx.x;

    // stage xin tile: pairs of lanes -> contiguous 32B per row, conflict-free LDS writes
    for (int v = tid; v < N_NODES * 2; v += 256) {
        int n = v >> 1, q = (v & 1) * 4;
        size_t g = (size_t)(row0 + b * N_NODES + n);
        float4 d;
        if (f0 < UNITS) {
            d = *(const float4*)(inp + g * 64 + f0 + q);
        } else {
            d = *(const float4*)(hx + g * 64 + (f0 - 64) + q);
            if (RMUL) {
                float4 r = *(const float4*)(r1 + (size_t)(b * N_NODES + n) * F_IN + (f0 - 64) + q);
                d.x *= r.x; d.y *= r.y; d.z *= r.z; d.w *= r.w;
            }
        }
        *(float4*)(ldsX + n * FT + q) = d;
    }
    __syncthreads();

    const int fg = tid & 1, mg = tid >> 1;
    const size_t tbase = ((size_t)b * NFT + blockIdx.x) * N_NODES;
    float4 accR[8];

    auto gather = [&](const int* __restrict__ cnt, const int* __restrict__ cols,
                      const float* __restrict__ vals, const float* __restrict__ src) {
        #pragma unroll
        for (int k = 0; k < 8; ++k) {
            int m = mg + k * 128;
            int nn = cnt[m];
            const int*   cm = cols + m * CAP;
            const float* vm = vals + m * CAP;
            float4 acc = make_float4(0.f, 0.f, 0.f, 0.f);
            for (int j = 0; j < nn; j += 8) {     // nn is a multiple of 8
                int4   c0 = *(const int4*)(cm + j);
                int4   c1 = *(const int4*)(cm + j + 4);
                float4 w0 = *(const float4*)(vm + j);
                float4 w1 = *(const float4*)(vm + j + 4);
                int   cc[8] = {c0.x, c0.y, c0.z, c0.w, c1.x, c1.y, c1.z, c1.w};
                float ww[8] = {w0.x, w0.y, w0.z, w0.w, w1.x, w1.y, w1.z, w1.w};
                #pragma unroll
                for (int u = 0; u < 8; ++u) {
                    float4 x = *(const float4*)(src + cc[u] * FT + fg * 4);
                    acc.x += ww[u] * x.x; acc.y += ww[u] * x.y;
                    acc.z += ww[u] * x.z; acc.w += ww[u] * x.w;
                }
            }
            accR[k] = acc;
        }
    };

    // A = L0 @ X  -> ldsT + global
    gather(cnt0, cols0, vals0, ldsX);
    #pragma unroll
    for (int k = 0; k < 8; ++k) {
        int m = mg + k * 128;
        *(float4*)(ldsT + m * FT + fg * 4) = accR[k];
        *(float4*)(A + (tbase + m) * FT + fg * 4) = accR[k];
    }
    __syncthreads();
    // C = L0 @ A (from ldsT) -> global
    gather(cnt0, cols0, vals0, ldsT);
    #pragma unroll
    for (int k = 0; k < 8; ++k)
        *(float4*)(C + (tbase + (mg + k * 128)) * FT + fg * 4) = accR[k];
    // B = L1 @ X (from ldsX, ldsT still being read by others -> regs first)
    gather(cnt1, cols1, vals1, ldsX);
    __syncthreads();
    #pragma unroll
    for (int k = 0; k < 8; ++k) {
        int m = mg + k * 128;
        *(float4*)(ldsT + m * FT + fg * 4) = accR[k];
        *(float4*)(Bm + (tbase + m) * FT + fg * 4) = accR[k];
    }
    __syncthreads();
    // D = L1 @ B (from ldsT) -> global
    gather(cnt1, cols1, vals1, ldsT);
    #pragma unroll
    for (int k = 0; k < 8; ++k)
        *(float4*)(D + (tbase + (mg + k * 128)) * FT + fg * 4) = accR[k];
}

// ---------------- Projection: out = act(bias + sum_m Xm @ W'[m]) -----------
// 128-row x NOUT tile per block, 256 threads; thread j-range split into
// JJ=NOUT/64 chunks at tx*4 (+64) -> 2-way (free) LDS reads.
template <int NOUT, int ACT, int RMUL>
__global__ __launch_bounds__(256, 4) void proj(
        const float* __restrict__ inp, const float* __restrict__ hx, const float* __restrict__ r1,
        const float* __restrict__ X1, const float* __restrict__ X2,
        const float* __restrict__ X3, const float* __restrict__ X4,
        const float* __restrict__ Wp, const float* __restrict__ bias,
        float* __restrict__ out, int row0) {
    __shared__ float xt[32][132];            // [k][i] transposed, padded
    __shared__ float wt[32][NOUT + 4];       // [k][j], padded
    constexpr int JJ = NOUT / 64;
    const int i0   = blockIdx.x * 128;       // chunk-local row base
    const int b    = i0 >> 10;               // 1024 % 128 == 0 -> same b per block
    const int nloc = i0 & 1023;
    const int tx = threadIdx.x & 15, ty = threadIdx.x >> 4;
    float acc[8][JJ][4];
    #pragma unroll
    for (int r = 0; r < 8; ++r)
        #pragma unroll
        for (int jj = 0; jj < JJ; ++jj)
            #pragma unroll
            for (int c = 0; c < 4; ++c) acc[r][jj][c] = 0.f;

    const float* Xs[4] = {X1, X2, X3, X4};
    #pragma unroll
    for (int m = 0; m < NUM_M; ++m) {
        for (int k0 = 0; k0 < F_IN; k0 += 32) {
            __syncthreads();
            // stage X tile transposed: wave sweeps i for fixed k-quad
            for (int v = threadIdx.x; v < 1024; v += 256) {
                int q = v >> 7, i = v & 127;
                int k = k0 + q * 4;
                float4 d;
                if (m == 0) {
                    size_t g = (size_t)(row0 + i0 + i);
                    if (k < 64) d = *(const float4*)(inp + g * 64 + k);
                    else {
                        d = *(const float4*)(hx + g * 64 + (k - 64));
                        if (RMUL) {
                            float4 r = *(const float4*)(r1 + (size_t)(i0 + i) * F_IN + (k - 64));
                            d.x *= r.x; d.y *= r.y; d.z *= r.z; d.w *= r.w;
                        }
                    }
                } else {
                    const float* Xm = Xs[m - 1];
                    int ft = k >> 3, kq = k & 7;
                    d = *(const float4*)(Xm + (((size_t)b * NFT + ft) * N_NODES + nloc + i) * FT + kq);
                }
                xt[q * 4 + 0][i] = d.x; xt[q * 4 + 1][i] = d.y;
                xt[q * 4 + 2][i] = d.z; xt[q * 4 + 3][i] = d.w;
            }
            // stage W tile
            const float* Wm = Wp + (size_t)m * F_IN * NOUT + (size_t)k0 * NOUT;
            for (int v = threadIdx.x; v < 32 * (NOUT / 4); v += 256) {
                int kk = v / (NOUT / 4), q = v % (NOUT / 4);
                float4 d = *(const float4*)(Wm + (size_t)kk * NOUT + q * 4);
                *(float4*)(&wt[kk][q * 4]) = d;
            }
            __syncthreads();
            for (int kk = 0; kk < 32; ++kk) {
                float xv[8];
                *(float4*)&xv[0] = *(const float4*)&xt[kk][ty * 8];
                *(float4*)&xv[4] = *(const float4*)&xt[kk][ty * 8 + 4];
                float wv[JJ][4];
                #pragma unroll
                for (int jj = 0; jj < JJ; ++jj)
                    *(float4*)&wv[jj][0] = *(const float4*)&wt[kk][jj * 64 + tx * 4];
                #pragma unroll
                for (int r = 0; r < 8; ++r)
                    #pragma unroll
                    for (int jj = 0; jj < JJ; ++jj)
                        #pragma unroll
                        for (int c = 0; c < 4; ++c)
                            acc[r][jj][c] += xv[r] * wv[jj][c];
            }
        }
    }
    float bv[JJ][4];
    #pragma unroll
    for (int jj = 0; jj < JJ; ++jj)
        *(float4*)&bv[jj][0] = *(const float4*)(bias + jj * 64 + tx * 4);
    #pragma unroll
    for (int r = 0; r < 8; ++r) {
        size_t row = (size_t)(i0 + ty * 8 + r);
        #pragma unroll
        for (int jj = 0; jj < JJ; ++jj) {
            float a0 = acc[r][jj][0] + bv[jj][0];
            float a1 = acc[r][jj][1] + bv[jj][1];
            float a2 = acc[r][jj][2] + bv[jj][2];
            float a3 = acc[r][jj][3] + bv[jj][3];
            float4 v;
            if (ACT) { v.x = tanhf(a0); v.y = tanhf(a1); v.z = tanhf(a2); v.w = tanhf(a3); }
            else {
                v.x = 1.f / (1.f + expf(-a0)); v.y = 1.f / (1.f + expf(-a1));
                v.z = 1.f / (1.f + expf(-a2)); v.w = 1.f / (1.f + expf(-a3));
            }
            *(float4*)(out + row * NOUT + jj * 64 + tx * 4) = v;
        }
    }
}

// ---------------- Final gating: out = u*hx + (1-u)*c -----------------------
__global__ void finalize(const float* __restrict__ OUT1, const float* __restrict__ OUT2,
                         const float* __restrict__ hx, float* __restrict__ out,
                         int row0, int nrows) {
    int t = blockIdx.x * blockDim.x + threadIdx.x;
    int total = nrows * 16;                  // 16 float4 per row of 64
    if (t >= total) return;
    int i = t >> 4, q = t & 15;
    size_t g = (size_t)(row0 + i);
    float4 u = *(const float4*)(OUT1 + (size_t)i * F_IN + 64 + q * 4);
    float4 c = *(const float4*)(OUT2 + (size_t)i * UNITS + q * 4);
    float4 h = *(const float4*)(hx + g * 64 + q * 4);
    float4 o;
    o.x = u.x * h.x + (1.f - u.x) * c.x;
    o.y = u.y * h.y + (1.f - u.y) * c.y;
    o.z = u.z * h.z + (1.f - u.z) * c.z;
    o.w = u.w * h.w + (1.f - u.w) * c.w;
    *(float4*)(out + g * 64 + q * 4) = o;
}

// ---------------------------------------------------------------------------
extern "C" void kernel_launch(void* const* d_in, const int* in_sizes, int n_in,
                              void* d_out, int out_size, void* d_ws, size_t ws_size,
                              hipStream_t stream) {
    const float* inp = (const float*)d_in[0];
    const float* hx  = (const float*)d_in[1];
    const float* L0  = (const float*)d_in[2];
    const float* L1  = (const float*)d_in[3];
    const float* W1  = (const float*)d_in[4];
    const float* b1  = (const float*)d_in[5];
    const float* W2  = (const float*)d_in[6];
    const float* b2  = (const float*)d_in[7];
    float* out = (float*)d_out;

    char* ws = (char*)d_ws;
    size_t off = 0;
    auto carve = [&](size_t bytes) -> char* {
        off = (off + 255) & ~(size_t)255;
        char* p = ws + off;
        off += bytes;
        return p;
    };
    // fixed region
    int*   cnt0  = (int*)  carve(N_NODES * sizeof(int));
    int*   cols0 = (int*)  carve((size_t)N_NODES * CAP * sizeof(int));
    float* vals0 = (float*)carve((size_t)N_NODES * CAP * sizeof(float));
    int*   cnt1  = (int*)  carve(N_NODES * sizeof(int));
    int*   cols1 = (int*)  carve((size_t)N_NODES * CAP * sizeof(int));
    float* vals1 = (float*)carve((size_t)N_NODES * CAP * sizeof(float));
    float* Wp1   = (float*)carve((size_t)NUM_M * F_IN * 128 * sizeof(float));
    float* Wp2   = (float*)carve((size_t)NUM_M * F_IN * 64 * sizeof(float));

    // dynamic chunking over batch: A,B,C,D tiled + OUT1 + OUT2
    size_t xb = (size_t)N_NODES * F_IN * sizeof(float);    // 512 KB
    size_t per_batch = xb * 5 + (size_t)N_NODES * UNITS * sizeof(float);
    size_t fixed_end = (off + 255) & ~(size_t)255;
    size_t avail = (ws_size > fixed_end + 4096) ? (ws_size - fixed_end - 4096) : per_batch;
    int Bc = (int)(avail / per_batch);
    if (Bc < 1) Bc = 1;
    if (Bc > BATCH) Bc = BATCH;

    float* A    = (float*)carve((size_t)Bc * xb);
    float* Bm   = (float*)carve((size_t)Bc * xb);
    float* C    = (float*)carve((size_t)Bc * xb);
    float* D    = (float*)carve((size_t)Bc * xb);
    float* OUT1 = (float*)carve((size_t)Bc * xb);                              // [bc*1024][128]
    float* OUT2 = (float*)carve((size_t)Bc * N_NODES * UNITS * sizeof(float)); // [bc*1024][64]

    ell_build<<<N_NODES / 4, 256, 0, stream>>>(L0, cnt0, cols0, vals0);
    ell_build<<<N_NODES / 4, 256, 0, stream>>>(L1, cnt1, cols1, vals1);
    wprep<<<(NUM_M * F_IN * 128 + 255) / 256, 256, 0, stream>>>(W1, Wp1, 128);
    wprep<<<(NUM_M * F_IN * 64 + 255) / 256, 256, 0, stream>>>(W2, Wp2, 64);

    for (int b0 = 0; b0 < BATCH; b0 += Bc) {
        int bc = (BATCH - b0 < Bc) ? (BATCH - b0) : Bc;
        int nrows = bc * N_NODES;
        int row0 = b0 * N_NODES;
        dim3 dg(NFT, bc);

        diffuse4<0><<<dg, 256, 0, stream>>>(cnt0, cols0, vals0, cnt1, cols1, vals1,
                                            inp, hx, nullptr, A, Bm, C, D, row0);
        proj<128, 0, 0><<<nrows / 128, 256, 0, stream>>>(inp, hx, nullptr,
                                                         A, Bm, C, D, Wp1, b1, OUT1, row0);
        diffuse4<1><<<dg, 256, 0, stream>>>(cnt0, cols0, vals0, cnt1, cols1, vals1,
                                            inp, hx, OUT1, A, Bm, C, D, row0);
        proj<64, 1, 1><<<nrows / 128, 256, 0, stream>>>(inp, hx, OUT1,
                                                        A, Bm, C, D, Wp2, b2, OUT2, row0);
        finalize<<<(nrows * 16 + 255) / 256, 256, 0, stream>>>(OUT1, OUT2, hx, out, row0, nrows);
    }
}